// Round 8
// baseline (87.870 us; speedup 1.0000x reference)
//
#include <hip/hip_runtime.h>

// MountainCar batched rollout: B=8192 envs, 500 sequential steps of a
// 2->64->1 MLP policy + dynamics. Mixed issue/latency bound at 2 waves/SIMD;
// per-step issue model: MLP block 32 cyc (41%), dynamics ~30, DPP 8, trans ~12.
//
// Round 8 = R7 skeleton (write-at-crossing, KL=16, intrinsic DPP butterfly,
// sign-free tanh, deferred reward) + PACKED-FP32 MLP: the 4 hidden units per
// lane are computed as two float2 ext-vectors -> v_pk_fma_f32 (1 instr per
// 2 f32). 16 -> ~11 instructions in the layer block if VOP3P-f32 is
// full-rate on gfx950 (this round doubles as that rate experiment).

typedef float v2f __attribute__((ext_vector_type(2)));

constexpr int B = 8192;
constexpr int L = 64;
constexpr int MAX_STEPS = 500;
constexpr float GOAL_P = 0.5f;
constexpr float MIN_P  = -1.2f;
constexpr float MIN_V  = -0.07f;
constexpr float MAX_V  = 0.07f;

constexpr int KL  = 16;       // lanes per env
constexpr int UPL = L / KL;   // hidden units per lane = 4 (= 2 x v2f)

template<int CTRL>
__device__ __forceinline__ float dpp_add(float x) {
  int y = __builtin_amdgcn_update_dpp(0, __float_as_int(x), CTRL, 0xf, 0xf, true);
  return x + __int_as_float(y);
}

__global__ __launch_bounds__(256) void mc_kernel(
    const float* __restrict__ x,  const float* __restrict__ w1,
    const float* __restrict__ b1, const float* __restrict__ w2,
    const float* __restrict__ b2, float* __restrict__ out)
{
  int tid  = blockIdx.x * blockDim.x + threadIdx.x;
  int env  = tid >> 4;                 // env index
  int sub  = tid & 15;                 // lane-within-env
  int lane = threadIdx.x & 63;         // lane-within-wave

  constexpr float TS = 2.8853900817779268f;  // 2*log2(e), folded into w2/b2

  // Packed weights: v2f k covers units (j0+2k, j0+2k+1).
  const v2f* w1v = reinterpret_cast<const v2f*>(w1);   // row-major 2x64
  const v2f* b1v = reinterpret_cast<const v2f*>(b1);
  const v2f* w2v = reinterpret_cast<const v2f*>(w2);
  const int q0 = sub * (UPL / 2);      // v2f index of this lane's first pair

  v2f w1a2[2], w1b2[2], b1r2[2], w2r2[2];
#pragma unroll
  for (int i = 0; i < 2; ++i) {
    w1a2[i] = w1v[q0 + i];             // w1[0][.]
    w1b2[i] = w1v[L / 2 + q0 + i];     // w1[1][.]
    b1r2[i] = b1v[q0 + i];
    v2f wv  = w2v[q0 + i];
    w2r2[i] = (v2f){wv.x * TS, wv.y * TS};
  }
  // b2 seeded into the .x half of lane 0's packed accumulator; the
  // horizontal add + butterfly distribute it (exactly one b2 in the total).
  const v2f sv0 = {(sub == 0) ? b2[0] * TS : 0.0f, 0.0f};

  float4 st = reinterpret_cast<const float4*>(x)[env];
  const float r0 = st.w;
  float p = st.x, v = st.y, u = st.z;
  float racc = 0.0f;   // sum of u^2 over live steps

  unsigned long long live = __ballot(true);

  for (int stp = 0; stp < MAX_STEPS; ++stp) {
    float p1 = fmaxf(p, MIN_P);
    float v1 = (p <= MIN_P) ? 0.0f : v;

    // cos(3*p1): v_cos takes revolutions; independent of the MLP chain.
    float c = __builtin_amdgcn_cosf(p1 * 0.47746482927568601f);

    // Layer 1 (relu) + layer 2, packed 2 units per instruction.
    v2f vp1 = {p1, p1}, vv1 = {v1, v1};
    v2f h0 = __builtin_elementwise_fma(vv1, w1b2[0],
             __builtin_elementwise_fma(vp1, w1a2[0], b1r2[0]));
    v2f h1 = __builtin_elementwise_fma(vv1, w1b2[1],
             __builtin_elementwise_fma(vp1, w1a2[1], b1r2[1]));
    h0 = __builtin_elementwise_max(h0, (v2f){0.0f, 0.0f});
    h1 = __builtin_elementwise_max(h1, (v2f){0.0f, 0.0f});
    v2f sv = __builtin_elementwise_fma(h1, w2r2[1],
             __builtin_elementwise_fma(h0, w2r2[0], sv0));
    float s = sv.x + sv.y;

    // 16-lane butterfly; every lane ends with the full pre-scaled logit.
    s = dpp_add<0xB1>(s);     // quad_perm [1,0,3,2] : + lane^1
    s = dpp_add<0x4E>(s);     // quad_perm [2,3,0,1] : + lane^2
    s = dpp_add<0x141>(s);    // row_half_mirror    : + lane^(4..7)
    s = dpp_add<0x140>(s);    // row_mirror         : + lane^(8..15)

    // tanh, sign-free: 1 - 2/(exp2(s)+1); exact at both saturations.
    float e  = __builtin_amdgcn_exp2f(s);
    float u1 = fmaf(-2.0f, __builtin_amdgcn_rcpf(e + 1.0f), 1.0f);

    float v2 = fmaf(-0.0025f, c, fmaf(0.0015f, u1, v1));
    v2 = __builtin_amdgcn_fmed3f(v2, MIN_V, MAX_V);

    // Unconditional state update.
    p = p1 + v2;
    v = v2;
    u = u1;
    racc = fmaf(u1, u1, racc);

    // Newly-crossed envs commit their final row immediately.
    unsigned long long crossed = __ballot(p > GOAL_P) & live;
    if (crossed) {                        // wave-uniform, rarely taken
      live &= ~crossed;
      if (((crossed >> lane) & 1ull) && sub == 0) {
        float rout = fmaf(-0.1f, racc, r0) + 100.0f;
        reinterpret_cast<float4*>(out)[env] = make_float4(p, v, u, rout);
      }
      if (!live) return;
    }
  }

  // Envs that never crossed within MAX_STEPS: no +100.
  if (((live >> lane) & 1ull) && sub == 0) {
    float rout = fmaf(-0.1f, racc, r0);
    reinterpret_cast<float4*>(out)[env] = make_float4(p, v, u, rout);
  }
}

extern "C" void kernel_launch(void* const* d_in, const int* in_sizes, int n_in,
                              void* d_out, int out_size, void* d_ws, size_t ws_size,
                              hipStream_t stream) {
  const float* x  = (const float*)d_in[0];
  const float* w1 = (const float*)d_in[1];
  const float* b1 = (const float*)d_in[2];
  const float* w2 = (const float*)d_in[3];
  const float* b2 = (const float*)d_in[4];
  float* out = (float*)d_out;

  constexpr int threads = B * KL;  // 131072 -> 2048 waves -> 2 waves/SIMD
  mc_kernel<<<threads / 256, 256, 0, stream>>>(x, w1, b1, w2, b2, out);
}